// Round 13
// baseline (295.294 us; speedup 1.0000x reference)
//
#include <hip/hip_runtime.h>
#include <hip/hip_fp16.h>
#include <hip/hip_fp8.h>

#define N_NODES 100000
#define N_EDGES 1600000
#define ET      (N_EDGES + N_NODES)   // edges + self-loops = 1,700,000
#define NG      512
#define SLOPE   0.2f

#define BKT_SHIFT 9                         // 512 nodes per bucket
#define NB_B   ((N_NODES + 511) / 512)      // 196 buckets
#define CHUNK_A 8192
#define NBLK_A ((ET + CHUNK_A - 1) / CHUNK_A)   // 208
#define H1B    ((N_NODES + 255) / 256)      // 391 mfma-h1 blocks (256 nodes each)

typedef _Float16 half8_t __attribute__((ext_vector_type(8)));
typedef float    f32x4_t __attribute__((ext_vector_type(4)));

// ---- fused: MFMA h1 = x@W1 (fp8 out) + logits  |  coarse bucket histogram ----
__global__ __launch_bounds__(256) void k_prep(
    const float* __restrict__ x, const float* __restrict__ W1,
    const float* __restrict__ a1s, const float* __restrict__ a1d,
    const int* __restrict__ ei,
    __hip_fp8_e4m3* __restrict__ h1, float* __restrict__ al1s, float* __restrict__ al1d,
    int* __restrict__ bsize)
{
    __shared__ float Wl[64 * 64];
    __shared__ float asf[64], adf[64];
    __shared__ int hcnt[NB_B];
    int tid = threadIdx.x;

    if (blockIdx.x >= H1B) {
        // ---------------- histogram role ----------------
        for (int i = tid; i < NB_B; i += 256) hcnt[i] = 0;
        __syncthreads();
        int base = (blockIdx.x - H1B) * CHUNK_A;
        int m = min(CHUNK_A, ET - base);
        for (int i = tid; i < m; i += 256) {
            int eid = base + i;
            int d = (eid < N_EDGES) ? ei[N_EDGES + eid] : (eid - N_EDGES);
            atomicAdd(&hcnt[d >> BKT_SHIFT], 1);
        }
        __syncthreads();
        for (int i = tid; i < NB_B; i += 256)
            if (hcnt[i]) atomicAdd(&bsize[i], hcnt[i]);
        return;
    }

    // ---------------- MFMA h1 role: 4 waves x 16 nodes x 4 iters ----------------
    for (int i = tid; i < 64 * 64; i += 256) Wl[i] = W1[i];
    if (tid < 64) { asf[tid] = a1s[tid]; adf[tid] = a1d[tid]; }
    __syncthreads();

    int wv = tid >> 6, lane = tid & 63;
    int m = lane & 15, q = lane >> 4;

    half8_t bf[4][2];
#pragma unroll
    for (int t = 0; t < 4; ++t)
#pragma unroll
        for (int s = 0; s < 2; ++s) {
            half8_t b;
#pragma unroll
            for (int j = 0; j < 8; ++j)
                b[j] = (_Float16)Wl[(s * 32 + q * 8 + j) * 64 + t * 16 + m];
            bf[t][s] = b;
        }

    for (int it = 0; it < 4; ++it) {
        int node0 = blockIdx.x * 256 + wv * 64 + it * 16;
        int node = node0 + m;
        half8_t av0 = {}, av1 = {};
        if (node < N_NODES) {
            const float4* xr = (const float4*)(x + (long long)node * 64);
            float4 p0 = xr[q * 2], p1 = xr[q * 2 + 1];
            float4 p2 = xr[q * 2 + 8], p3 = xr[q * 2 + 9];
            av0[0] = (_Float16)p0.x; av0[1] = (_Float16)p0.y;
            av0[2] = (_Float16)p0.z; av0[3] = (_Float16)p0.w;
            av0[4] = (_Float16)p1.x; av0[5] = (_Float16)p1.y;
            av0[6] = (_Float16)p1.z; av0[7] = (_Float16)p1.w;
            av1[0] = (_Float16)p2.x; av1[1] = (_Float16)p2.y;
            av1[2] = (_Float16)p2.z; av1[3] = (_Float16)p2.w;
            av1[4] = (_Float16)p3.x; av1[5] = (_Float16)p3.y;
            av1[6] = (_Float16)p3.z; av1[7] = (_Float16)p3.w;
        }
        f32x4_t acc[4] = {{0,0,0,0},{0,0,0,0},{0,0,0,0},{0,0,0,0}};
#pragma unroll
        for (int t = 0; t < 4; ++t) {
            acc[t] = __builtin_amdgcn_mfma_f32_16x16x32_f16(av0, bf[t][0], acc[t], 0, 0, 0);
            acc[t] = __builtin_amdgcn_mfma_f32_16x16x32_f16(av1, bf[t][1], acc[t], 0, 0, 0);
        }
#pragma unroll
        for (int r = 0; r < 4; ++r) {
            int nr = node0 + q * 4 + r;
            bool ok = nr < N_NODES;
#pragma unroll
            for (int t = 0; t < 4; ++t) {
                float v = acc[t][r];
                if (ok) h1[(long long)nr * 64 + t * 16 + m] = __hip_fp8_e4m3(v);
                float ps = v * asf[t * 16 + m];
                float pd = v * adf[t * 16 + m];
                ps += __shfl_xor(ps, 1); ps += __shfl_xor(ps, 2);
                ps += __shfl_xor(ps, 4); ps += __shfl_xor(ps, 8);
                pd += __shfl_xor(pd, 1); pd += __shfl_xor(pd, 2);
                pd += __shfl_xor(pd, 4); pd += __shfl_xor(pd, 8);
                if (ok && m == t) { al1s[nr * 4 + t] = ps; al1d[nr * 4 + t] = pd; }
            }
        }
    }
}

// ---------------- scan of bucket sizes (1 block) ----------------
__global__ __launch_bounds__(256) void k_scanB(const int* __restrict__ bsize,
                                               int* __restrict__ bbase, int* __restrict__ bcur)
{
    __shared__ int tmp[256];
    int tid = threadIdx.x;
    int v = (tid < NB_B) ? bsize[tid] : 0;
    tmp[tid] = v;
    __syncthreads();
    for (int off = 1; off < 256; off <<= 1) {
        int t = (tid >= off) ? tmp[tid - off] : 0;
        __syncthreads();
        tmp[tid] += t;
        __syncthreads();
    }
    if (tid < NB_B) { int e = tmp[tid] - v; bbase[tid] = e; bcur[tid] = e; }
}

// ---- pass A: LDS counting sort of 8K-edge chunks (1024 threads) ----
__global__ __launch_bounds__(1024) void k_passA(const int* __restrict__ ei,
                                                int* __restrict__ bcur, unsigned int* __restrict__ ebuf)
{
    __shared__ unsigned int stage[CHUNK_A];     // 32 KB
    __shared__ unsigned char sbin[CHUNK_A];     // 8 KB
    __shared__ int hist[NB_B];
    __shared__ int binst[NB_B];
    __shared__ int resv[NB_B];
    __shared__ int cur[NB_B];
    __shared__ int tmp[1024];
    int tid = threadIdx.x;
    int base = blockIdx.x * CHUNK_A;
    int m = min(CHUNK_A, ET - base);
    for (int i = tid; i < NB_B; i += 1024) hist[i] = 0;
    __syncthreads();
    for (int i = tid; i < m; i += 1024) {
        int eid = base + i;
        int d = (eid < N_EDGES) ? ei[N_EDGES + eid] : (eid - N_EDGES);
        atomicAdd(&hist[d >> BKT_SHIFT], 1);
    }
    __syncthreads();
    int v = (tid < NB_B) ? hist[tid] : 0;
    tmp[tid] = v;
    __syncthreads();
    for (int off = 1; off < 1024; off <<= 1) {
        int t = (tid >= off) ? tmp[tid - off] : 0;
        __syncthreads();
        tmp[tid] += t;
        __syncthreads();
    }
    if (tid < NB_B) {
        int e = tmp[tid] - v;
        binst[tid] = e;
        cur[tid] = e;
        resv[tid] = v ? atomicAdd(&bcur[tid], v) : 0;   // ~196 atomics / block
    }
    __syncthreads();
    for (int i = tid; i < m; i += 1024) {
        int eid = base + i;
        int s, d;
        if (eid < N_EDGES) { s = ei[eid]; d = ei[N_EDGES + eid]; }
        else               { s = eid - N_EDGES; d = s; }
        int b = d >> BKT_SHIFT;
        int pos = atomicAdd(&cur[b], 1);
        stage[pos] = ((unsigned int)(d & 511) << 17) | (unsigned int)s;
        sbin[pos] = (unsigned char)b;
    }
    __syncthreads();
    for (int i = tid; i < m; i += 1024) {
        int b = sbin[i];
        ebuf[resv[b] + (i - binst[b])] = stage[i];
    }
}

// ---- pass B: per-bucket node hist+scan + csr scatter (1024 threads) ----
__global__ __launch_bounds__(1024) void k_passB(
    const unsigned int* __restrict__ ebuf, const int* __restrict__ bbase,
    const int* __restrict__ bsize,
    int* __restrict__ csr, int* __restrict__ offs, int* __restrict__ deg)
{
    __shared__ int ldeg[512];
    __shared__ int lofs[512];
    __shared__ int lcur[512];
    int tid = threadIdx.x;
    int b = blockIdx.x;
    int nb0 = b << BKT_SHIFT;
    int nn = min(512, N_NODES - nb0);
    int gbase = bbase[b], cnt = bsize[b];
    if (tid < 512) ldeg[tid] = 0;
    __syncthreads();
    for (int i = tid; i < cnt; i += 1024)
        atomicAdd(&ldeg[ebuf[gbase + i] >> 17], 1);
    __syncthreads();
    int v = 0;
    if (tid < 512) { v = ldeg[tid]; lofs[tid] = v; }
    __syncthreads();
    for (int off = 1; off < 512; off <<= 1) {
        int t = (tid >= off && tid < 512) ? lofs[tid - off] : 0;
        __syncthreads();
        if (tid < 512) lofs[tid] += t;
        __syncthreads();
    }
    if (tid < 512) {
        int e = lofs[tid] - v;                  // exclusive
        lcur[tid] = e;
        if (tid < nn) { offs[nb0 + tid] = gbase + e; deg[nb0 + tid] = v; }
    }
    __syncthreads();
    for (int i = tid; i < cnt; i += 1024) {
        unsigned int ev = ebuf[gbase + i];
        int dl = ev >> 17, s = (int)(ev & 0x1FFFF);
        int p = atomicAdd(&lcur[dl], 1);
        csr[gbase + p] = s;
    }
}

// ---- layer 1 aggregate: 4 edges/iter x 16 lanes/edge x 4 fp8-ch/lane ----
__global__ __launch_bounds__(256) void k_agg1(
    const int* __restrict__ offs, const int* __restrict__ deg, const int* __restrict__ csr,
    const __hip_fp8_e4m3* __restrict__ h1, const float* __restrict__ al1s, const float* __restrict__ al1d,
    const float* __restrict__ b1, const float* __restrict__ W2,
    const float* __restrict__ a2s, const float* __restrict__ a2d,
    __half* __restrict__ h2, float* __restrict__ al2s, float* __restrict__ al2d)
{
    __shared__ float W2l[64 * 16];
    __shared__ int   sarr[4][64];       // s*64 (pre-scaled byte row offset)
    __shared__ float warr[4][4 * 72];   // [wave][head*72 + j]: 72-stride -> 16 distinct banks
    __shared__ float h1b[4][64];
    __shared__ float h2s[4][16];
    int tid = threadIdx.x;
    for (int i = tid; i < 64 * 16; i += 256) W2l[i] = W2[i];
    __syncthreads();                    // only barrier: W2l is cross-wave

    int wv = tid >> 6, lane = tid & 63;
    int eslot = lane >> 4;              // which of 4 edges per iteration
    int cq = lane & 15;                 // channel quad: channels 4cq..4cq+3
    int h = cq >> 2;                    // head of this channel quad
    int cq4 = cq * 4;
    int node = blockIdx.x * 4 + wv;
    int st = offs[node], dg = deg[node];
    const float4 ald4 = *(const float4*)(al1d + node * 4);
    const char* __restrict__ h1c = (const char*)h1;

    float a0 = 0.f, a1 = 0.f, a2 = 0.f, a3 = 0.f, den = 0.f;
    for (int base = 0; base < dg; base += 64) {
        int m = min(64, dg - base);
        int s = 0;
        float w0 = 0.f, w1 = 0.f, w2 = 0.f, w3 = 0.f;
        if (lane < m) {
            s = csr[st + base + lane];              // coalesced
            const float4 as4 = *(const float4*)(al1s + s * 4);  // 16B gather (L2-resident)
            float e0 = as4.x + ald4.x; e0 = e0 > 0.f ? e0 : SLOPE * e0;
            float e1 = as4.y + ald4.y; e1 = e1 > 0.f ? e1 : SLOPE * e1;
            float e2 = as4.z + ald4.z; e2 = e2 > 0.f ? e2 : SLOPE * e2;
            float e3 = as4.w + ald4.w; e3 = e3 > 0.f ? e3 : SLOPE * e3;
            w0 = __expf(e0); w1 = __expf(e1); w2 = __expf(e2); w3 = __expf(e3);
        }
        sarr[wv][lane] = s << 6;                    // pad lanes: s=0, w=0
        warr[wv][0 * 72 + lane] = w0;
        warr[wv][1 * 72 + lane] = w1;
        warr[wv][2 * 72 + lane] = w2;
        warr[wv][3 * 72 + lane] = w3;
        // intra-wave LDS dependency only — no barrier (trip counts diverge per wave)
        int m4 = (m + 3) & ~3;
#pragma unroll 4
        for (int j0 = 0; j0 < m4; j0 += 4) {
            int j = j0 + eslot;
            int off = sarr[wv][j] + cq4;            // 4-addr broadcast + add
            float wgt = warr[wv][h * 72 + j];       // 16 distinct banks, 4-lane bcast
            unsigned int pk = *(const unsigned int*)(h1c + off);  // 64B/edge, 4 lines in flight
            a0 = fmaf(wgt, __builtin_amdgcn_cvt_f32_fp8(pk, 0), a0);
            a1 = fmaf(wgt, __builtin_amdgcn_cvt_f32_fp8(pk, 1), a1);
            a2 = fmaf(wgt, __builtin_amdgcn_cvt_f32_fp8(pk, 2), a2);
            a3 = fmaf(wgt, __builtin_amdgcn_cvt_f32_fp8(pk, 3), a3);
            den += wgt;
        }
    }
    // reduce over the 4 edge-slots
    a0 += __shfl_xor(a0, 16); a0 += __shfl_xor(a0, 32);
    a1 += __shfl_xor(a1, 16); a1 += __shfl_xor(a1, 32);
    a2 += __shfl_xor(a2, 16); a2 += __shfl_xor(a2, 32);
    a3 += __shfl_xor(a3, 16); a3 += __shfl_xor(a3, 32);
    den += __shfl_xor(den, 16); den += __shfl_xor(den, 32);
    if (lane < 16) {                                // lane == cq
        float inv = 1.f / (den + 1e-16f);
        float v0 = a0 * inv + b1[cq4 + 0]; v0 = v0 > 0.f ? v0 : expm1f(v0);
        float v1 = a1 * inv + b1[cq4 + 1]; v1 = v1 > 0.f ? v1 : expm1f(v1);
        float v2 = a2 * inv + b1[cq4 + 2]; v2 = v2 > 0.f ? v2 : expm1f(v2);
        float v3 = a3 * inv + b1[cq4 + 3]; v3 = v3 > 0.f ? v3 : expm1f(v3);
        h1b[wv][cq4 + 0] = v0; h1b[wv][cq4 + 1] = v1;
        h1b[wv][cq4 + 2] = v2; h1b[wv][cq4 + 3] = v3;
    }
    // intra-wave: no barrier needed
    if (lane < 16) {
        float a = 0.f;
#pragma unroll
        for (int k = 0; k < 64; ++k) a = fmaf(h1b[wv][k], W2l[k * 16 + lane], a);
        h2[node * 16 + lane] = __float2half_rn(a);
        h2s[wv][lane] = a;
    }
    if (lane == 0) {
        float s2 = 0.f, d2 = 0.f;
#pragma unroll
        for (int j = 0; j < 16; ++j) {
            float v2 = h2s[wv][j];
            s2 = fmaf(v2, a2s[j], s2);
            d2 = fmaf(v2, a2d[j], d2);
        }
        al2s[node] = s2;
        al2d[node] = d2;
    }
}

// ---- layer 2 aggregate: 8 edges/iter, fp16 h2 (3.2MB, L2-resident) ----
__global__ __launch_bounds__(256) void k_agg2(
    const int* __restrict__ offs, const int* __restrict__ deg, const int* __restrict__ csr,
    const __half* __restrict__ h2, const float* __restrict__ al2s, const float* __restrict__ al2d,
    const float* __restrict__ b2, float* __restrict__ hout)
{
    __shared__ int   sarr[4][64];
    __shared__ float warr[4][64];
    int tid = threadIdx.x;
    int wv = tid >> 6, lane = tid & 63;
    int ec = lane >> 3, cc = lane & 7;  // 8 edges x 8 channel-pairs
    int node = blockIdx.x * 4 + wv;
    int st = offs[node], dg = deg[node];
    float ald = al2d[node];
    const __half2* __restrict__ h2v = (const __half2*)h2;

    float a0 = 0.f, a1 = 0.f, den = 0.f;
    for (int base = 0; base < dg; base += 64) {
        int m = min(64, dg - base);
        int s = 0; float wl = 0.f;
        if (lane < m) {
            s = csr[st + base + lane];              // coalesced
            float e = al2s[s] + ald;                // 64 independent gathers (L2-resident)
            e = e > 0.f ? e : SLOPE * e;
            wl = __expf(e);
        }
        sarr[wv][lane] = s;                         // pad: s=0, w=0
        warr[wv][lane] = wl;
        float t = wl;
#pragma unroll
        for (int x = 1; x < 64; x <<= 1) t += __shfl_xor(t, x);
        den += t;
        int m8 = (m + 7) & ~7;
#pragma unroll 2
        for (int j0 = 0; j0 < m8; j0 += 8) {
            int j = j0 + ec;
            int s2i = sarr[wv][j];                  // 8-addr broadcast
            float wgt = warr[wv][j];
            __half2 hv = h2v[s2i * 8 + cc];         // 32B row, 8 rows in flight
            a0 = fmaf(__low2float(hv), wgt, a0);
            a1 = fmaf(__high2float(hv), wgt, a1);
        }
    }
    a0 += __shfl_xor(a0, 8);  a1 += __shfl_xor(a1, 8);
    a0 += __shfl_xor(a0, 16); a1 += __shfl_xor(a1, 16);
    a0 += __shfl_xor(a0, 32); a1 += __shfl_xor(a1, 32);
    if (lane < 8) {
        float inv = 1.f / (den + 1e-16f);
        float v0 = a0 * inv + b2[2 * cc];
        float v1 = a1 * inv + b2[2 * cc + 1];
        v0 = v0 > 0.f ? v0 : expm1f(v0);    // ELU
        v1 = v1 > 0.f ? v1 : expm1f(v1);
        ((float2*)hout)[node * 8 + cc] = make_float2(v0, v1);  // coalesced
    }
}

// ---- mean-pool per graph (binary-search node range) + classifier ----
__global__ __launch_bounds__(256) void k_pool(
    const float* __restrict__ hout, const int* __restrict__ batch,
    const float* __restrict__ Wc, const float* __restrict__ bc, float* __restrict__ out)
{
    __shared__ float red[16][17];
    __shared__ int bnd[2];
    int g = blockIdx.x;
    int t = threadIdx.x, c = t & 15, slot = t >> 4;
    if (t < 2) {
        int key = g + t;                // lower_bound(batch, g) and (g+1)
        int lo = 0, hi = N_NODES;
        while (lo < hi) { int mid = (lo + hi) >> 1; if (batch[mid] < key) lo = mid + 1; else hi = mid; }
        bnd[t] = lo;
    }
    __syncthreads();
    int s = bnd[0], e = bnd[1];
    float sum = 0.f;
    for (int n = s + slot; n < e; n += 16)
        sum += hout[n * 16 + c];        // fully coalesced (1 KB / iter / block)
    red[slot][c] = sum;
    __syncthreads();
    if (t < 16) {
        float tot = 0.f;
#pragma unroll
        for (int k = 0; k < 16; ++k) tot += red[k][t];
        float cnt = fmaxf((float)(e - s), 1.0f);
        float pc = (tot / cnt) * Wc[t];
        pc += __shfl_xor(pc, 1); pc += __shfl_xor(pc, 2);
        pc += __shfl_xor(pc, 4); pc += __shfl_xor(pc, 8);
        if (t == 0) out[g] = pc + bc[0];
    }
}

extern "C" void kernel_launch(void* const* d_in, const int* in_sizes, int n_in,
                              void* d_out, int out_size, void* d_ws, size_t ws_size,
                              hipStream_t stream)
{
    const float* x    = (const float*)d_in[0];
    const int*   ei   = (const int*)d_in[1];
    const int*   batc = (const int*)d_in[2];
    const float* W1   = (const float*)d_in[3];
    const float* a1s  = (const float*)d_in[4];
    const float* a1d  = (const float*)d_in[5];
    const float* b1   = (const float*)d_in[6];
    const float* W2   = (const float*)d_in[7];
    const float* a2s  = (const float*)d_in[8];
    const float* a2d  = (const float*)d_in[9];
    const float* b2   = (const float*)d_in[10];
    const float* Wc   = (const float*)d_in[11];
    const float* bc   = (const float*)d_in[12];
    float* out = (float*)d_out;

    // ---- workspace carve, 16B-aligned chunks. Zero region first, one memset. ----
    char* ws = (char*)d_ws;
    size_t off = 0;
    auto carveB = [&](size_t bytes) {
        void* p = ws + off;
        off += ((bytes + 15) & ~(size_t)15);
        return p;
    };
    auto carve = [&](size_t elems) { return carveB(elems * 4); };
    int*   bsize  = (int*)  carve(NB_B);           // zeroed
    size_t zero_bytes = off;
    int*   bbase  = (int*)  carve(NB_B);
    int*   bcur   = (int*)  carve(NB_B);
    unsigned int* ebuf = (unsigned int*)carve(ET);
    int*   csr    = (int*)  carve(ET);
    int*   offs   = (int*)  carve(N_NODES);
    int*   deg    = (int*)  carve(N_NODES);
    __hip_fp8_e4m3* h1 = (__hip_fp8_e4m3*)carveB((size_t)N_NODES * 64);
    float* al1s   = (float*)carve((size_t)N_NODES * 4);
    float* al1d   = (float*)carve((size_t)N_NODES * 4);
    __half* h2    = (__half*)carveB((size_t)N_NODES * 16 * 2);
    float* al2s   = (float*)carve(N_NODES);
    float* al2d   = (float*)carve(N_NODES);
    float* hout   = (float*)carve((size_t)N_NODES * 16);

    hipMemsetAsync(d_ws, 0, zero_bytes, stream);

    k_prep <<<H1B + NBLK_A, 256, 0, stream>>>(x, W1, a1s, a1d, ei, h1, al1s, al1d, bsize);
    k_scanB<<<1, 256, 0, stream>>>(bsize, bbase, bcur);
    k_passA<<<NBLK_A, 1024, 0, stream>>>(ei, bcur, ebuf);
    k_passB<<<NB_B, 1024, 0, stream>>>(ebuf, bbase, bsize, csr, offs, deg);
    k_agg1 <<<N_NODES / 4, 256, 0, stream>>>(offs, deg, csr, h1, al1s, al1d,
                                             b1, W2, a2s, a2d, h2, al2s, al2d);
    k_agg2 <<<N_NODES / 4, 256, 0, stream>>>(offs, deg, csr, h2, al2s, al2d,
                                             b2, hout);
    k_pool <<<NG, 256, 0, stream>>>(hout, batc, Wc, bc, out);
}

// Round 15
// 257.592 us; speedup vs baseline: 1.1464x; 1.1464x over previous
//
#include <hip/hip_runtime.h>
#include <hip/hip_fp16.h>
#include <hip/hip_fp8.h>

#define N_NODES 100000
#define N_EDGES 1600000
#define ET      (N_EDGES + N_NODES)   // edges + self-loops = 1,700,000
#define NG      512
#define SLOPE   0.2f

#define BKT_SHIFT 9                         // 512 nodes per bucket
#define NB_B   ((N_NODES + 511) / 512)      // 196 buckets
#define CHUNK_A 8192
#define NBLK_A ((ET + CHUNK_A - 1) / CHUNK_A)   // 208
#define H1B    ((N_NODES + 255) / 256)      // 391 mfma-h1 blocks (256 nodes each)

typedef _Float16 half8_t __attribute__((ext_vector_type(8)));
typedef float    f32x4_t __attribute__((ext_vector_type(4)));

// ---- fused: MFMA h1 = x@W1 (fp8 out) + logits  |  coarse bucket histogram ----
__global__ __launch_bounds__(256) void k_prep(
    const float* __restrict__ x, const float* __restrict__ W1,
    const float* __restrict__ a1s, const float* __restrict__ a1d,
    const int* __restrict__ ei,
    __hip_fp8_e4m3* __restrict__ h1, float* __restrict__ al1s, float* __restrict__ al1d,
    int* __restrict__ bsize)
{
    __shared__ float Wl[64 * 64];
    __shared__ float asf[64], adf[64];
    __shared__ int hcnt[NB_B];
    int tid = threadIdx.x;

    if (blockIdx.x >= H1B) {
        // ---------------- histogram role ----------------
        for (int i = tid; i < NB_B; i += 256) hcnt[i] = 0;
        __syncthreads();
        int base = (blockIdx.x - H1B) * CHUNK_A;
        int m = min(CHUNK_A, ET - base);
        for (int i = tid; i < m; i += 256) {
            int eid = base + i;
            int d = (eid < N_EDGES) ? ei[N_EDGES + eid] : (eid - N_EDGES);
            atomicAdd(&hcnt[d >> BKT_SHIFT], 1);
        }
        __syncthreads();
        for (int i = tid; i < NB_B; i += 256)
            if (hcnt[i]) atomicAdd(&bsize[i], hcnt[i]);
        return;
    }

    // ---------------- MFMA h1 role: 4 waves x 16 nodes x 4 iters ----------------
    for (int i = tid; i < 64 * 64; i += 256) Wl[i] = W1[i];
    if (tid < 64) { asf[tid] = a1s[tid]; adf[tid] = a1d[tid]; }
    __syncthreads();

    int wv = tid >> 6, lane = tid & 63;
    int m = lane & 15, q = lane >> 4;

    half8_t bf[4][2];
#pragma unroll
    for (int t = 0; t < 4; ++t)
#pragma unroll
        for (int s = 0; s < 2; ++s) {
            half8_t b;
#pragma unroll
            for (int j = 0; j < 8; ++j)
                b[j] = (_Float16)Wl[(s * 32 + q * 8 + j) * 64 + t * 16 + m];
            bf[t][s] = b;
        }

    for (int it = 0; it < 4; ++it) {
        int node0 = blockIdx.x * 256 + wv * 64 + it * 16;
        int node = node0 + m;
        half8_t av0 = {}, av1 = {};
        if (node < N_NODES) {
            const float4* xr = (const float4*)(x + (long long)node * 64);
            float4 p0 = xr[q * 2], p1 = xr[q * 2 + 1];
            float4 p2 = xr[q * 2 + 8], p3 = xr[q * 2 + 9];
            av0[0] = (_Float16)p0.x; av0[1] = (_Float16)p0.y;
            av0[2] = (_Float16)p0.z; av0[3] = (_Float16)p0.w;
            av0[4] = (_Float16)p1.x; av0[5] = (_Float16)p1.y;
            av0[6] = (_Float16)p1.z; av0[7] = (_Float16)p1.w;
            av1[0] = (_Float16)p2.x; av1[1] = (_Float16)p2.y;
            av1[2] = (_Float16)p2.z; av1[3] = (_Float16)p2.w;
            av1[4] = (_Float16)p3.x; av1[5] = (_Float16)p3.y;
            av1[6] = (_Float16)p3.z; av1[7] = (_Float16)p3.w;
        }
        f32x4_t acc[4] = {{0,0,0,0},{0,0,0,0},{0,0,0,0},{0,0,0,0}};
#pragma unroll
        for (int t = 0; t < 4; ++t) {
            acc[t] = __builtin_amdgcn_mfma_f32_16x16x32_f16(av0, bf[t][0], acc[t], 0, 0, 0);
            acc[t] = __builtin_amdgcn_mfma_f32_16x16x32_f16(av1, bf[t][1], acc[t], 0, 0, 0);
        }
#pragma unroll
        for (int r = 0; r < 4; ++r) {
            int nr = node0 + q * 4 + r;
            bool ok = nr < N_NODES;
#pragma unroll
            for (int t = 0; t < 4; ++t) {
                float v = acc[t][r];
                if (ok) h1[(long long)nr * 64 + t * 16 + m] = __hip_fp8_e4m3(v);
                float ps = v * asf[t * 16 + m];
                float pd = v * adf[t * 16 + m];
                ps += __shfl_xor(ps, 1); ps += __shfl_xor(ps, 2);
                ps += __shfl_xor(ps, 4); ps += __shfl_xor(ps, 8);
                pd += __shfl_xor(pd, 1); pd += __shfl_xor(pd, 2);
                pd += __shfl_xor(pd, 4); pd += __shfl_xor(pd, 8);
                if (ok && m == t) { al1s[nr * 4 + t] = ps; al1d[nr * 4 + t] = pd; }
            }
        }
    }
}

// ---------------- scan of bucket sizes (1 block) ----------------
__global__ __launch_bounds__(256) void k_scanB(const int* __restrict__ bsize,
                                               int* __restrict__ bbase, int* __restrict__ bcur)
{
    __shared__ int tmp[256];
    int tid = threadIdx.x;
    int v = (tid < NB_B) ? bsize[tid] : 0;
    tmp[tid] = v;
    __syncthreads();
    for (int off = 1; off < 256; off <<= 1) {
        int t = (tid >= off) ? tmp[tid - off] : 0;
        __syncthreads();
        tmp[tid] += t;
        __syncthreads();
    }
    if (tid < NB_B) { int e = tmp[tid] - v; bbase[tid] = e; bcur[tid] = e; }
}

// ---- pass A: LDS counting sort of 8K-edge chunks (1024 threads) ----
__global__ __launch_bounds__(1024) void k_passA(const int* __restrict__ ei,
                                                int* __restrict__ bcur, unsigned int* __restrict__ ebuf)
{
    __shared__ unsigned int stage[CHUNK_A];     // 32 KB
    __shared__ unsigned char sbin[CHUNK_A];     // 8 KB
    __shared__ int hist[NB_B];
    __shared__ int binst[NB_B];
    __shared__ int resv[NB_B];
    __shared__ int cur[NB_B];
    __shared__ int tmp[1024];
    int tid = threadIdx.x;
    int base = blockIdx.x * CHUNK_A;
    int m = min(CHUNK_A, ET - base);
    for (int i = tid; i < NB_B; i += 1024) hist[i] = 0;
    __syncthreads();
    for (int i = tid; i < m; i += 1024) {
        int eid = base + i;
        int d = (eid < N_EDGES) ? ei[N_EDGES + eid] : (eid - N_EDGES);
        atomicAdd(&hist[d >> BKT_SHIFT], 1);
    }
    __syncthreads();
    int v = (tid < NB_B) ? hist[tid] : 0;
    tmp[tid] = v;
    __syncthreads();
    for (int off = 1; off < 1024; off <<= 1) {
        int t = (tid >= off) ? tmp[tid - off] : 0;
        __syncthreads();
        tmp[tid] += t;
        __syncthreads();
    }
    if (tid < NB_B) {
        int e = tmp[tid] - v;
        binst[tid] = e;
        cur[tid] = e;
        resv[tid] = v ? atomicAdd(&bcur[tid], v) : 0;   // ~196 atomics / block
    }
    __syncthreads();
    for (int i = tid; i < m; i += 1024) {
        int eid = base + i;
        int s, d;
        if (eid < N_EDGES) { s = ei[eid]; d = ei[N_EDGES + eid]; }
        else               { s = eid - N_EDGES; d = s; }
        int b = d >> BKT_SHIFT;
        int pos = atomicAdd(&cur[b], 1);
        stage[pos] = ((unsigned int)(d & 511) << 17) | (unsigned int)s;
        sbin[pos] = (unsigned char)b;
    }
    __syncthreads();
    for (int i = tid; i < m; i += 1024) {
        int b = sbin[i];
        ebuf[resv[b] + (i - binst[b])] = stage[i];
    }
}

// ---- pass B: per-bucket node hist+scan + csr scatter (1024 threads) ----
__global__ __launch_bounds__(1024) void k_passB(
    const unsigned int* __restrict__ ebuf, const int* __restrict__ bbase,
    const int* __restrict__ bsize,
    int* __restrict__ csr, int* __restrict__ offs, int* __restrict__ deg)
{
    __shared__ int ldeg[512];
    __shared__ int lofs[512];
    __shared__ int lcur[512];
    int tid = threadIdx.x;
    int b = blockIdx.x;
    int nb0 = b << BKT_SHIFT;
    int nn = min(512, N_NODES - nb0);
    int gbase = bbase[b], cnt = bsize[b];
    if (tid < 512) ldeg[tid] = 0;
    __syncthreads();
    for (int i = tid; i < cnt; i += 1024)
        atomicAdd(&ldeg[ebuf[gbase + i] >> 17], 1);
    __syncthreads();
    int v = 0;
    if (tid < 512) { v = ldeg[tid]; lofs[tid] = v; }
    __syncthreads();
    for (int off = 1; off < 512; off <<= 1) {
        int t = (tid >= off && tid < 512) ? lofs[tid - off] : 0;
        __syncthreads();
        if (tid < 512) lofs[tid] += t;
        __syncthreads();
    }
    if (tid < 512) {
        int e = lofs[tid] - v;                  // exclusive
        lcur[tid] = e;
        if (tid < nn) { offs[nb0 + tid] = gbase + e; deg[nb0 + tid] = v; }
    }
    __syncthreads();
    for (int i = tid; i < cnt; i += 1024) {
        unsigned int ev = ebuf[gbase + i];
        int dl = ev >> 17, s = (int)(ev & 0x1FFFF);
        int p = atomicAdd(&lcur[dl], 1);
        csr[gbase + p] = s;
    }
}

// ---- layer 1 aggregate: 4 edges/iter x 16 lanes/edge, slim all-lane epilogue ----
__global__ __launch_bounds__(256) void k_agg1(
    const int* __restrict__ offs, const int* __restrict__ deg, const int* __restrict__ csr,
    const __hip_fp8_e4m3* __restrict__ h1, const float* __restrict__ al1s, const float* __restrict__ al1d,
    const float* __restrict__ b1, __half* __restrict__ h1bg)
{
    __shared__ int   sarr[4][64];       // s*64 (pre-scaled byte row offset)
    __shared__ float warr[4][4 * 72];   // [wave][head*72 + j]: conflict-free
    __shared__ __align__(16) float h1b[4][64];
    int tid = threadIdx.x;
    int wv = tid >> 6, lane = tid & 63;
    int eslot = lane >> 4;              // which of 4 edges per iteration
    int cq = lane & 15;                 // channel quad: channels 4cq..4cq+3
    int h = cq >> 2;                    // head of this channel quad
    int cq4 = cq * 4;
    int node = blockIdx.x * 4 + wv;
    int st = offs[node], dg = deg[node];
    const float4 ald4 = *(const float4*)(al1d + node * 4);
    float b1l = b1[lane];               // coalesced, L1-hot
    const char* __restrict__ h1c = (const char*)h1;

    float a0 = 0.f, a1 = 0.f, a2 = 0.f, a3 = 0.f, den = 0.f;
    for (int base = 0; base < dg; base += 64) {
        int m = min(64, dg - base);
        int s = 0;
        float w0 = 0.f, w1 = 0.f, w2 = 0.f, w3 = 0.f;
        if (lane < m) {
            s = csr[st + base + lane];              // coalesced
            const float4 as4 = *(const float4*)(al1s + s * 4);  // 16B gather (L2-resident)
            float e0 = as4.x + ald4.x; e0 = e0 > 0.f ? e0 : SLOPE * e0;
            float e1 = as4.y + ald4.y; e1 = e1 > 0.f ? e1 : SLOPE * e1;
            float e2 = as4.z + ald4.z; e2 = e2 > 0.f ? e2 : SLOPE * e2;
            float e3 = as4.w + ald4.w; e3 = e3 > 0.f ? e3 : SLOPE * e3;
            w0 = __expf(e0); w1 = __expf(e1); w2 = __expf(e2); w3 = __expf(e3);
        }
        sarr[wv][lane] = s << 6;                    // pad lanes: s=0, w=0
        warr[wv][0 * 72 + lane] = w0;
        warr[wv][1 * 72 + lane] = w1;
        warr[wv][2 * 72 + lane] = w2;
        warr[wv][3 * 72 + lane] = w3;
        // intra-wave LDS dependency only — no barrier (trip counts diverge per wave)
        int m4 = (m + 3) & ~3;
#pragma unroll 4
        for (int j0 = 0; j0 < m4; j0 += 4) {
            int j = j0 + eslot;
            int off = sarr[wv][j] + cq4;            // 4-addr broadcast + add
            float wgt = warr[wv][h * 72 + j];       // 16 distinct banks, 4-lane bcast
            unsigned int pk = *(const unsigned int*)(h1c + off);  // 64B/edge
            a0 = fmaf(wgt, __builtin_amdgcn_cvt_f32_fp8(pk, 0), a0);
            a1 = fmaf(wgt, __builtin_amdgcn_cvt_f32_fp8(pk, 1), a1);
            a2 = fmaf(wgt, __builtin_amdgcn_cvt_f32_fp8(pk, 2), a2);
            a3 = fmaf(wgt, __builtin_amdgcn_cvt_f32_fp8(pk, 3), a3);
            den += wgt;
        }
    }
    // reduce over the 4 edge-slots; den[lane] = full denom for head (lane&15)>>2
    a0 += __shfl_xor(a0, 16); a0 += __shfl_xor(a0, 32);
    a1 += __shfl_xor(a1, 16); a1 += __shfl_xor(a1, 32);
    a2 += __shfl_xor(a2, 16); a2 += __shfl_xor(a2, 32);
    a3 += __shfl_xor(a3, 16); a3 += __shfl_xor(a3, 32);
    den += __shfl_xor(den, 16); den += __shfl_xor(den, 32);
    if (lane < 16)
        *(float4*)&h1b[wv][cq4] = make_float4(a0, a1, a2, a3);
    // channel `lane` needs head lane>>4's denominator: lane 4h holds head h's den
    float denc = __shfl(den, (lane >> 4) << 2);
    // intra-wave LDS, no barrier
    float v = h1b[wv][lane] / (denc + 1e-16f) + b1l;
    v = v > 0.f ? v : __expf(v) - 1.f;  // fast ELU
    h1bg[(long long)node * 64 + lane] = __float2half_rn(v);  // coalesced 128B
}

// ---- MFMA: h2 = h1b @ W2 (fp16 out) + layer-2 logits. 16 nodes/wave ----
__global__ __launch_bounds__(256) void k_mid(
    const __half* __restrict__ h1bg, const float* __restrict__ W2,
    const float* __restrict__ a2s, const float* __restrict__ a2d,
    __half* __restrict__ h2, float* __restrict__ al2s, float* __restrict__ al2d)
{
    __shared__ float W2l[64 * 16];
    int tid = threadIdx.x;
    for (int i = tid; i < 64 * 16; i += 256) W2l[i] = W2[i];
    __syncthreads();
    int wv = tid >> 6, lane = tid & 63;
    int m = lane & 15, q = lane >> 4;
    // B-frag: lane holds B[k = s*32 + q*8 + j][n = m]
    half8_t bf[2];
#pragma unroll
    for (int s = 0; s < 2; ++s) {
        half8_t b;
#pragma unroll
        for (int j = 0; j < 8; ++j)
            b[j] = (_Float16)W2l[(s * 32 + q * 8 + j) * 16 + m];
        bf[s] = b;
    }
    int node0 = blockIdx.x * 64 + wv * 16;
    half8_t av0 = {}, av1 = {};
    if (node0 + m < N_NODES) {
        const __half* ar = h1bg + (long long)(node0 + m) * 64;
        av0 = *(const half8_t*)(ar + q * 8);        // 16B coalesced
        av1 = *(const half8_t*)(ar + 32 + q * 8);
    }
    f32x4_t acc = {0, 0, 0, 0};
    acc = __builtin_amdgcn_mfma_f32_16x16x32_f16(av0, bf[0], acc, 0, 0, 0);
    acc = __builtin_amdgcn_mfma_f32_16x16x32_f16(av1, bf[1], acc, 0, 0, 0);
    float a2sm = a2s[m], a2dm = a2d[m];
    // C: col=m (h2 channel), row=q*4+r (node within tile)
#pragma unroll
    for (int r = 0; r < 4; ++r) {
        int nr = node0 + q * 4 + r;
        bool ok = nr < N_NODES;
        float v = acc[r];
        if (ok) h2[nr * 16 + m] = __float2half_rn(v);
        float ps = v * a2sm, pd = v * a2dm;
        ps += __shfl_xor(ps, 1); ps += __shfl_xor(ps, 2);
        ps += __shfl_xor(ps, 4); ps += __shfl_xor(ps, 8);
        pd += __shfl_xor(pd, 1); pd += __shfl_xor(pd, 2);
        pd += __shfl_xor(pd, 4); pd += __shfl_xor(pd, 8);
        if (ok && m == 0) { al2s[nr] = ps; al2d[nr] = pd; }
    }
}

// ---- layer 2 aggregate: 8 edges/iter, fp16 h2 (3.2MB, L2-resident) ----
__global__ __launch_bounds__(256) void k_agg2(
    const int* __restrict__ offs, const int* __restrict__ deg, const int* __restrict__ csr,
    const __half* __restrict__ h2, const float* __restrict__ al2s, const float* __restrict__ al2d,
    const float* __restrict__ b2, float* __restrict__ hout)
{
    __shared__ int   sarr[4][64];
    __shared__ float warr[4][64];
    int tid = threadIdx.x;
    int wv = tid >> 6, lane = tid & 63;
    int ec = lane >> 3, cc = lane & 7;  // 8 edges x 8 channel-pairs
    int node = blockIdx.x * 4 + wv;
    int st = offs[node], dg = deg[node];
    float ald = al2d[node];
    const __half2* __restrict__ h2v = (const __half2*)h2;

    float a0 = 0.f, a1 = 0.f, den = 0.f;
    for (int base = 0; base < dg; base += 64) {
        int m = min(64, dg - base);
        int s = 0; float wl = 0.f;
        if (lane < m) {
            s = csr[st + base + lane];              // coalesced
            float e = al2s[s] + ald;                // 64 independent gathers (L2-resident)
            e = e > 0.f ? e : SLOPE * e;
            wl = __expf(e);
        }
        sarr[wv][lane] = s;                         // pad: s=0, w=0
        warr[wv][lane] = wl;
        float t = wl;
#pragma unroll
        for (int x = 1; x < 64; x <<= 1) t += __shfl_xor(t, x);
        den += t;
        int m8 = (m + 7) & ~7;
#pragma unroll 2
        for (int j0 = 0; j0 < m8; j0 += 8) {
            int j = j0 + ec;
            int s2i = sarr[wv][j];                  // 8-addr broadcast
            float wgt = warr[wv][j];
            __half2 hv = h2v[s2i * 8 + cc];         // 32B row, 8 rows in flight
            a0 = fmaf(__low2float(hv), wgt, a0);
            a1 = fmaf(__high2float(hv), wgt, a1);
        }
    }
    a0 += __shfl_xor(a0, 8);  a1 += __shfl_xor(a1, 8);
    a0 += __shfl_xor(a0, 16); a1 += __shfl_xor(a1, 16);
    a0 += __shfl_xor(a0, 32); a1 += __shfl_xor(a1, 32);
    if (lane < 8) {
        float inv = 1.f / (den + 1e-16f);
        float v0 = a0 * inv + b2[2 * cc];
        float v1 = a1 * inv + b2[2 * cc + 1];
        v0 = v0 > 0.f ? v0 : __expf(v0) - 1.f;  // fast ELU
        v1 = v1 > 0.f ? v1 : __expf(v1) - 1.f;
        ((float2*)hout)[node * 8 + cc] = make_float2(v0, v1);  // coalesced
    }
}

// ---- mean-pool per graph (binary-search node range) + classifier ----
__global__ __launch_bounds__(256) void k_pool(
    const float* __restrict__ hout, const int* __restrict__ batch,
    const float* __restrict__ Wc, const float* __restrict__ bc, float* __restrict__ out)
{
    __shared__ float red[16][17];
    __shared__ int bnd[2];
    int g = blockIdx.x;
    int t = threadIdx.x, c = t & 15, slot = t >> 4;
    if (t < 2) {
        int key = g + t;                // lower_bound(batch, g) and (g+1)
        int lo = 0, hi = N_NODES;
        while (lo < hi) { int mid = (lo + hi) >> 1; if (batch[mid] < key) lo = mid + 1; else hi = mid; }
        bnd[t] = lo;
    }
    __syncthreads();
    int s = bnd[0], e = bnd[1];
    float sum = 0.f;
    for (int n = s + slot; n < e; n += 16)
        sum += hout[n * 16 + c];        // fully coalesced (1 KB / iter / block)
    red[slot][c] = sum;
    __syncthreads();
    if (t < 16) {
        float tot = 0.f;
#pragma unroll
        for (int k = 0; k < 16; ++k) tot += red[k][t];
        float cnt = fmaxf((float)(e - s), 1.0f);
        float pc = (tot / cnt) * Wc[t];
        pc += __shfl_xor(pc, 1); pc += __shfl_xor(pc, 2);
        pc += __shfl_xor(pc, 4); pc += __shfl_xor(pc, 8);
        if (t == 0) out[g] = pc + bc[0];
    }
}

extern "C" void kernel_launch(void* const* d_in, const int* in_sizes, int n_in,
                              void* d_out, int out_size, void* d_ws, size_t ws_size,
                              hipStream_t stream)
{
    const float* x    = (const float*)d_in[0];
    const int*   ei   = (const int*)d_in[1];
    const int*   batc = (const int*)d_in[2];
    const float* W1   = (const float*)d_in[3];
    const float* a1s  = (const float*)d_in[4];
    const float* a1d  = (const float*)d_in[5];
    const float* b1   = (const float*)d_in[6];
    const float* W2   = (const float*)d_in[7];
    const float* a2s  = (const float*)d_in[8];
    const float* a2d  = (const float*)d_in[9];
    const float* b2   = (const float*)d_in[10];
    const float* Wc   = (const float*)d_in[11];
    const float* bc   = (const float*)d_in[12];
    float* out = (float*)d_out;

    // ---- workspace carve, 16B-aligned chunks. Zero region first, one memset. ----
    char* ws = (char*)d_ws;
    size_t off = 0;
    auto carveB = [&](size_t bytes) {
        void* p = ws + off;
        off += ((bytes + 15) & ~(size_t)15);
        return p;
    };
    auto carve = [&](size_t elems) { return carveB(elems * 4); };
    int*   bsize  = (int*)  carve(NB_B);           // zeroed
    size_t zero_bytes = off;
    int*   bbase  = (int*)  carve(NB_B);
    int*   bcur   = (int*)  carve(NB_B);
    unsigned int* ebuf = (unsigned int*)carve(ET);
    int*   csr    = (int*)  carve(ET);
    int*   offs   = (int*)  carve(N_NODES);
    int*   deg    = (int*)  carve(N_NODES);
    __hip_fp8_e4m3* h1 = (__hip_fp8_e4m3*)carveB((size_t)N_NODES * 64);
    float* al1s   = (float*)carve((size_t)N_NODES * 4);
    float* al1d   = (float*)carve((size_t)N_NODES * 4);
    __half* h1bg  = (__half*)carveB((size_t)N_NODES * 64 * 2);
    __half* h2    = (__half*)carveB((size_t)N_NODES * 16 * 2);
    float* al2s   = (float*)carve(N_NODES);
    float* al2d   = (float*)carve(N_NODES);
    float* hout   = (float*)carve((size_t)N_NODES * 16);

    hipMemsetAsync(d_ws, 0, zero_bytes, stream);

    k_prep <<<H1B + NBLK_A, 256, 0, stream>>>(x, W1, a1s, a1d, ei, h1, al1s, al1d, bsize);
    k_scanB<<<1, 256, 0, stream>>>(bsize, bbase, bcur);
    k_passA<<<NBLK_A, 1024, 0, stream>>>(ei, bcur, ebuf);
    k_passB<<<NB_B, 1024, 0, stream>>>(ebuf, bbase, bsize, csr, offs, deg);
    k_agg1 <<<N_NODES / 4, 256, 0, stream>>>(offs, deg, csr, h1, al1s, al1d, b1, h1bg);
    k_mid  <<<(N_NODES + 63) / 64, 256, 0, stream>>>(h1bg, W2, a2s, a2d, h2, al2s, al2d);
    k_agg2 <<<N_NODES / 4, 256, 0, stream>>>(offs, deg, csr, h2, al2s, al2d,
                                             b2, hout);
    k_pool <<<NG, 256, 0, stream>>>(hout, batc, Wc, bc, out);
}